// Round 5
// baseline (8691.709 us; speedup 1.0000x reference)
//
#include <hip/hip_runtime.h>

#define BB    2      // batches
#define NN    8192   // points per batch
#define CC    64     // extra feature channels
#define NPT   1024   // npoint
#define NT    128    // 64-wide tiles per dim (8192/64)
#define NBLK  8      // fallback: blocks per batch
#define TPB   1024   // fallback: threads per block (1 point per thread)

// monotonic order-preserving key for f32 (handles negatives)
__device__ __forceinline__ unsigned int fkey(float v) {
  unsigned int u = __float_as_uint(v);
  return (u & 0x80000000u) ? ~u : (u | 0x80000000u);
}

// ======================= two-phase path (needs 512 MiB ws) =======================

// D[b][i][j] = n_i + n_j - 2*dot(A_i,A_j); all three accumulated by ascending-k
// fmaf chains over identical tile values -> D[i][i] == 0 bit-exactly.
__global__ __launch_bounds__(256) void dist_kernel(
    const float* __restrict__ pts, const float* __restrict__ feat,
    float* __restrict__ D) {
  __shared__ __align__(16) float Ai[67][64];
  __shared__ __align__(16) float Aj[67][64];
  __shared__ float ni_s[64], nj_s[64];
  const int bid = blockIdx.x;
  const int b   = bid >> 14;            // NT*NT = 16384 tiles per batch
  const int rem = bid & 16383;
  const int bi  = rem >> 7, bj = rem & (NT - 1);
  const int t   = threadIdx.x;
  const int i0  = bi * 64, j0 = bj * 64;
  const float* Pb = pts  + (size_t)b * NN * 3;
  const float* Fb = feat + (size_t)b * CC * NN;

  for (int idx = t; idx < 67 * 64; idx += 256) {
    const int c = idx >> 6, r = idx & 63;
    float vi, vj;
    if (c < 3) {
      vi = Pb[(size_t)(i0 + r) * 3 + c];
      vj = Pb[(size_t)(j0 + r) * 3 + c];
    } else {
      vi = Fb[(size_t)(c - 3) * NN + i0 + r];
      vj = Fb[(size_t)(c - 3) * NN + j0 + r];
    }
    Ai[c][r] = vi;
    Aj[c][r] = vj;
  }
  __syncthreads();

  // in-tile norms, same ascending-k fmaf order as the dot below
  if (t < 64) {
    float n = 0.f;
#pragma unroll
    for (int k = 0; k < 67; ++k) n = fmaf(Ai[k][t], Ai[k][t], n);
    ni_s[t] = n;
  } else if (t < 128) {
    const int r = t - 64;
    float n = 0.f;
#pragma unroll
    for (int k = 0; k < 67; ++k) n = fmaf(Aj[k][r], Aj[k][r], n);
    nj_s[r] = n;
  }
  __syncthreads();

  const int tx = t & 15, ty = t >> 4;
  float acc[4][4] = {};
  for (int k = 0; k < 67; ++k) {
    const float4 a = *(const float4*)&Ai[k][ty * 4];
    const float4 v = *(const float4*)&Aj[k][tx * 4];
    acc[0][0] = fmaf(a.x, v.x, acc[0][0]); acc[0][1] = fmaf(a.x, v.y, acc[0][1]);
    acc[0][2] = fmaf(a.x, v.z, acc[0][2]); acc[0][3] = fmaf(a.x, v.w, acc[0][3]);
    acc[1][0] = fmaf(a.y, v.x, acc[1][0]); acc[1][1] = fmaf(a.y, v.y, acc[1][1]);
    acc[1][2] = fmaf(a.y, v.z, acc[1][2]); acc[1][3] = fmaf(a.y, v.w, acc[1][3]);
    acc[2][0] = fmaf(a.z, v.x, acc[2][0]); acc[2][1] = fmaf(a.z, v.y, acc[2][1]);
    acc[2][2] = fmaf(a.z, v.z, acc[2][2]); acc[2][3] = fmaf(a.z, v.w, acc[2][3]);
    acc[3][0] = fmaf(a.w, v.x, acc[3][0]); acc[3][1] = fmaf(a.w, v.y, acc[3][1]);
    acc[3][2] = fmaf(a.w, v.z, acc[3][2]); acc[3][3] = fmaf(a.w, v.w, acc[3][3]);
  }

  const float4 nj4 = *(const float4*)&nj_s[tx * 4];
  float* Db = D + ((size_t)b << 26);
#pragma unroll
  for (int r = 0; r < 4; ++r) {
    const float nir = ni_s[ty * 4 + r];
    float4 w;
    w.x = (nir + nj4.x) - 2.0f * acc[r][0];
    w.y = (nir + nj4.y) - 2.0f * acc[r][1];
    w.z = (nir + nj4.z) - 2.0f * acc[r][2];
    w.w = (nir + nj4.w) - 2.0f * acc[r][3];
    *(float4*)&Db[(size_t)(i0 + ty * 4 + r) * NN + j0 + tx * 4] = w;
  }
}

// one block per batch: serial FPS scan over precomputed rows, block-local sync only
__global__ __launch_bounds__(1024) void scan_kernel(
    const float* __restrict__ D, int* __restrict__ out) {
  const int b = blockIdx.x;
  const int tid = threadIdx.x, lane = tid & 63, wid = tid >> 6;
  __shared__ unsigned long long wred[16];
  __shared__ int far_sh;
  const float* Db = D + ((size_t)b << 26);

  float4 m0 = {3.0e38f, 3.0e38f, 3.0e38f, 3.0e38f};
  float4 m1 = m0;
  if (tid == 0) out[b * NPT] = 0;
  int far = 0;

  for (int s = 1; s < NPT; ++s) {
    const float4* row = (const float4*)(Db + (size_t)far * NN);
    const float4 v0 = row[tid];
    const float4 v1 = row[1024 + tid];
    m0.x = fminf(m0.x, v0.x); m0.y = fminf(m0.y, v0.y);
    m0.z = fminf(m0.z, v0.z); m0.w = fminf(m0.w, v0.w);
    m1.x = fminf(m1.x, v1.x); m1.y = fminf(m1.y, v1.y);
    m1.z = fminf(m1.z, v1.z); m1.w = fminf(m1.w, v1.w);

    const int ja = tid * 4, jb = 4096 + tid * 4;
    unsigned long long k, o;
    k = ((unsigned long long)fkey(m0.x) << 13) | (unsigned int)(8191 - ja);
    o = ((unsigned long long)fkey(m0.y) << 13) | (unsigned int)(8191 - (ja + 1)); k = k > o ? k : o;
    o = ((unsigned long long)fkey(m0.z) << 13) | (unsigned int)(8191 - (ja + 2)); k = k > o ? k : o;
    o = ((unsigned long long)fkey(m0.w) << 13) | (unsigned int)(8191 - (ja + 3)); k = k > o ? k : o;
    o = ((unsigned long long)fkey(m1.x) << 13) | (unsigned int)(8191 - jb);       k = k > o ? k : o;
    o = ((unsigned long long)fkey(m1.y) << 13) | (unsigned int)(8191 - (jb + 1)); k = k > o ? k : o;
    o = ((unsigned long long)fkey(m1.z) << 13) | (unsigned int)(8191 - (jb + 2)); k = k > o ? k : o;
    o = ((unsigned long long)fkey(m1.w) << 13) | (unsigned int)(8191 - (jb + 3)); k = k > o ? k : o;

#pragma unroll
    for (int off = 1; off < 64; off <<= 1) {
      o = __shfl_xor(k, off);
      k = k > o ? k : o;
    }
    if (lane == 0) wred[wid] = k;
    __syncthreads();
    if (wid == 0) {
      unsigned long long v = (lane < 16) ? wred[lane] : 0ull;
#pragma unroll
      for (int off = 8; off; off >>= 1) {
        o = __shfl_xor(v, off);
        v = v > o ? v : o;
      }
      if (lane == 0) {
        const int fr = 8191 - (int)(v & 0x1FFFu);
        far_sh = fr;
        out[b * NPT + s] = fr;
      }
    }
    __syncthreads();
    far = far_sh;
  }
}

// ======================= fallback path (small ws) =======================
// register-resident features, 8 blocks/batch, single-cache-line consensus.

#define R64(M) \
  M(0) M(1) M(2) M(3) M(4) M(5) M(6) M(7) \
  M(8) M(9) M(10) M(11) M(12) M(13) M(14) M(15) \
  M(16) M(17) M(18) M(19) M(20) M(21) M(22) M(23) \
  M(24) M(25) M(26) M(27) M(28) M(29) M(30) M(31) \
  M(32) M(33) M(34) M(35) M(36) M(37) M(38) M(39) \
  M(40) M(41) M(42) M(43) M(44) M(45) M(46) M(47) \
  M(48) M(49) M(50) M(51) M(52) M(53) M(54) M(55) \
  M(56) M(57) M(58) M(59) M(60) M(61) M(62) M(63)

__global__ __attribute__((amdgpu_waves_per_eu(1, 4))) __launch_bounds__(TPB)
void fps_fallback(const float* __restrict__ pts, const float* __restrict__ feat,
                  int* __restrict__ out, unsigned long long* __restrict__ slots) {
  const int blk  = blockIdx.x & (NBLK - 1);
  const int b    = blockIdx.x >> 3;
  const int tid  = threadIdx.x;
  const int lane = tid & 63;
  const int wid  = tid >> 6;          // 0..15
  const int p    = blk * TPB + tid;

  const float* Pp = pts  + (size_t)b * NN * 3 + (size_t)p * 3;
  const float* Fp = feat + (size_t)b * CC * NN + p;

  float fx = Pp[0], fy = Pp[1], fz = Pp[2];
#define DCF(i) float fc##i = Fp[(i) * NN];
  R64(DCF)
#undef DCF
  asm volatile("" : "+v"(fx), "+v"(fy), "+v"(fz));
#define PIN(i) asm volatile("" : "+v"(fc##i));
  R64(PIN)
#undef PIN

  float nrm = 0.f;
  nrm += fx * fx; nrm += fy * fy; nrm += fz * fz;
#define NR(i) nrm += fc##i * fc##i;
  R64(NR)
#undef NR

  __shared__ unsigned long long wred[TPB / 64];
  __shared__ int far_sh;

  if (blk == 0 && tid == 0) out[b * NPT] = 0;

  float mind = 3.0e38f;
  int far = 0;

  for (int s = 1; s < NPT; ++s) {
    const int fu = __builtin_amdgcn_readfirstlane(far);
    const float* Pq = pts  + (size_t)b * NN * 3 + (size_t)fu * 3;
    const float* Fq = feat + (size_t)b * CC * NN + fu;
    const float gx = Pq[0], gy = Pq[1], gz = Pq[2];
#define GL(i) const float gc##i = Fq[(i) * NN];
    R64(GL)
#undef GL
    float nf = 0.f, dot = 0.f;
    nf += gx * gx; nf += gy * gy; nf += gz * gz;
#define NF(i) nf += gc##i * gc##i;
    R64(NF)
#undef NF
    dot += fx * gx; dot += fy * gy; dot += fz * gz;
#define DT(i) dot += fc##i * gc##i;
    R64(DT)
#undef DT
    const float d = (nf + nrm) - 2.0f * dot;
    mind = fminf(mind, d);

    unsigned long long key =
        ((unsigned long long)fkey(mind) << 13) | (unsigned int)(8191 - p);
#pragma unroll
    for (int off = 1; off < 64; off <<= 1) {
      unsigned long long o = __shfl_xor(key, off);
      key = key > o ? key : o;
    }
    if (lane == 0) wred[wid] = key;
    __syncthreads();

    if (wid == 0) {
      // block reduce (16 wave keys held in lanes 0..15)
      unsigned long long v = (lane < 16) ? wred[lane] : 0ull;
#pragma unroll
      for (int off = 8; off; off >>= 1) {
        unsigned long long o = __shfl_xor(v, off);
        v = v > o ? v : o;
      }
      // publish: tag+key are one atomic word -> RELAXED suffices
      unsigned long long* sb = slots + ((size_t)(s & 1) * BB + b) * NBLK;
      if (lane == 0) {
        v |= ((unsigned long long)s << 45);
        __hip_atomic_store(&sb[blk], v, __ATOMIC_RELAXED, __HIP_MEMORY_SCOPE_AGENT);
      }
      // poll the single 64B line of 8 slots
      unsigned long long g = 0;
      for (;;) {
        if (lane < NBLK)
          g = __hip_atomic_load(&sb[lane], __ATOMIC_RELAXED, __HIP_MEMORY_SCOPE_AGENT);
        const bool ok = (lane < NBLK) ? ((g >> 45) == (unsigned long long)s) : true;
        if (__all(ok)) break;
      }
#pragma unroll
      for (int off = 4; off; off >>= 1) {
        unsigned long long o = __shfl_xor(g, off);
        g = g > o ? g : o;
      }
      if (lane == 0) {
        const int fr = 8191 - (int)(g & 0x1FFFu);
        far_sh = fr;
        if (blk == 0) out[b * NPT + s] = fr;
      }
    }
    __syncthreads();
    far = far_sh;
  }
}

// ======================= host =======================

extern "C" void kernel_launch(void* const* d_in, const int* in_sizes, int n_in,
                              void* d_out, int out_size, void* d_ws, size_t ws_size,
                              hipStream_t stream) {
  const float* pts  = (const float*)d_in[0];
  const float* feat = (const float*)d_in[1];
  int* out = (int*)d_out;

  const size_t needD = ((size_t)BB << 26) * sizeof(float);  // exactly 512 MiB
  if (ws_size >= needD) {
    float* D = (float*)d_ws;
    dist_kernel<<<BB * NT * NT, 256, 0, stream>>>(pts, feat, D);
    scan_kernel<<<BB, 1024, 0, stream>>>(D, out);
  } else {
    unsigned long long* slots = (unsigned long long*)d_ws; // [2][BB][NBLK] = 256 B
    hipMemsetAsync(d_ws, 0, 2 * BB * NBLK * sizeof(unsigned long long), stream);
    void* args[] = {(void*)&pts, (void*)&feat, (void*)&out, (void*)&slots};
    dim3 grid(BB * NBLK), block(TPB);
    hipLaunchCooperativeKernel((void*)fps_fallback, grid, block, args, 0, stream);
  }
}

// Round 6
// 3996.397 us; speedup vs baseline: 2.1749x; 2.1749x over previous
//
#include <hip/hip_runtime.h>

#define BB    2      // batches
#define NN    8192   // points per batch
#define CC    64     // extra feature channels
#define NPT   1024   // npoint
#define NT    128    // 64-wide tiles per dim (8192/64)
#define NBLK  16     // fallback: blocks per batch
#define TPB   512    // fallback: threads per block (1 point per thread)

// monotonic order-preserving key for f32 (handles negatives)
__device__ __forceinline__ unsigned int fkey(float v) {
  unsigned int u = __float_as_uint(v);
  return (u & 0x80000000u) ? ~u : (u | 0x80000000u);
}

// ======================= D-path: dist build (per batch) =======================
// D[i][j] = n_i + n_j - 2*dot(A_i,A_j); norms and dots all accumulated by
// ascending-k fmaf chains over identical tile values -> D[i][i] == 0 bit-exactly,
// and values bit-match the (absmax=0-verified) fallback formula.
__global__ __launch_bounds__(256) void dist_kernel(
    const float* __restrict__ Pb,    // (N,3) for this batch
    const float* __restrict__ Fb,    // (C,N) for this batch
    float* __restrict__ Db) {        // (N,N) out
  __shared__ __align__(16) float Ai[67][64];
  __shared__ __align__(16) float Aj[67][64];
  __shared__ float ni_s[64], nj_s[64];
  const int bid = blockIdx.x;
  const int bi  = bid >> 7, bj = bid & (NT - 1);
  const int t   = threadIdx.x;
  const int i0  = bi * 64, j0 = bj * 64;

  for (int idx = t; idx < 67 * 64; idx += 256) {
    const int c = idx >> 6, r = idx & 63;
    float vi, vj;
    if (c < 3) {
      vi = Pb[(size_t)(i0 + r) * 3 + c];
      vj = Pb[(size_t)(j0 + r) * 3 + c];
    } else {
      vi = Fb[(size_t)(c - 3) * NN + i0 + r];
      vj = Fb[(size_t)(c - 3) * NN + j0 + r];
    }
    Ai[c][r] = vi;
    Aj[c][r] = vj;
  }
  __syncthreads();

  // in-tile norms, same ascending-k fmaf order as the dot below
  if (t < 64) {
    float n = 0.f;
#pragma unroll
    for (int k = 0; k < 67; ++k) n = fmaf(Ai[k][t], Ai[k][t], n);
    ni_s[t] = n;
  } else if (t < 128) {
    const int r = t - 64;
    float n = 0.f;
#pragma unroll
    for (int k = 0; k < 67; ++k) n = fmaf(Aj[k][r], Aj[k][r], n);
    nj_s[r] = n;
  }
  __syncthreads();

  const int tx = t & 15, ty = t >> 4;
  float acc[4][4] = {};
  for (int k = 0; k < 67; ++k) {
    const float4 a = *(const float4*)&Ai[k][ty * 4];
    const float4 v = *(const float4*)&Aj[k][tx * 4];
    acc[0][0] = fmaf(a.x, v.x, acc[0][0]); acc[0][1] = fmaf(a.x, v.y, acc[0][1]);
    acc[0][2] = fmaf(a.x, v.z, acc[0][2]); acc[0][3] = fmaf(a.x, v.w, acc[0][3]);
    acc[1][0] = fmaf(a.y, v.x, acc[1][0]); acc[1][1] = fmaf(a.y, v.y, acc[1][1]);
    acc[1][2] = fmaf(a.y, v.z, acc[1][2]); acc[1][3] = fmaf(a.y, v.w, acc[1][3]);
    acc[2][0] = fmaf(a.z, v.x, acc[2][0]); acc[2][1] = fmaf(a.z, v.y, acc[2][1]);
    acc[2][2] = fmaf(a.z, v.z, acc[2][2]); acc[2][3] = fmaf(a.z, v.w, acc[2][3]);
    acc[3][0] = fmaf(a.w, v.x, acc[3][0]); acc[3][1] = fmaf(a.w, v.y, acc[3][1]);
    acc[3][2] = fmaf(a.w, v.z, acc[3][2]); acc[3][3] = fmaf(a.w, v.w, acc[3][3]);
  }

  const float4 nj4 = *(const float4*)&nj_s[tx * 4];
#pragma unroll
  for (int r = 0; r < 4; ++r) {
    const float nir = ni_s[ty * 4 + r];
    float4 w;
    w.x = (nir + nj4.x) - 2.0f * acc[r][0];
    w.y = (nir + nj4.y) - 2.0f * acc[r][1];
    w.z = (nir + nj4.z) - 2.0f * acc[r][2];
    w.w = (nir + nj4.w) - 2.0f * acc[r][3];
    *(float4*)&Db[(size_t)(i0 + ty * 4 + r) * NN + j0 + tx * 4] = w;
  }
}

// ======================= D-path: serial scan =======================
// One block per batch; all sync is block-local (no cross-XCD traffic in the loop).
__global__ __launch_bounds__(512) void scan_kernel(
    const float* __restrict__ D, unsigned long long dstride,
    int* __restrict__ out, int ostride) {
  const int b = blockIdx.x;
  const float* Db = D + (size_t)b * dstride;
  int* ob = out + (size_t)b * ostride;
  const int tid = threadIdx.x, lane = tid & 63, wid = tid >> 6;  // 8 waves
  __shared__ unsigned long long wred[8];
  __shared__ int far_sh;

  float4 m[4];
#pragma unroll
  for (int k = 0; k < 4; ++k) m[k] = make_float4(3.0e38f, 3.0e38f, 3.0e38f, 3.0e38f);

  if (tid == 0) ob[0] = 0;
  int far = 0;

  for (int s = 1; s < NPT; ++s) {
    const float4* row = (const float4*)(Db + (size_t)far * NN);
    unsigned long long k64 = 0;
#pragma unroll
    for (int k = 0; k < 4; ++k) {
      const float4 v = row[tid + 512 * k];
      m[k].x = fminf(m[k].x, v.x);
      m[k].y = fminf(m[k].y, v.y);
      m[k].z = fminf(m[k].z, v.z);
      m[k].w = fminf(m[k].w, v.w);
      const int j = (tid + 512 * k) * 4;
      unsigned long long o;
      o = ((unsigned long long)fkey(m[k].x) << 13) | (unsigned int)(8191 - j);       k64 = k64 > o ? k64 : o;
      o = ((unsigned long long)fkey(m[k].y) << 13) | (unsigned int)(8191 - (j + 1)); k64 = k64 > o ? k64 : o;
      o = ((unsigned long long)fkey(m[k].z) << 13) | (unsigned int)(8191 - (j + 2)); k64 = k64 > o ? k64 : o;
      o = ((unsigned long long)fkey(m[k].w) << 13) | (unsigned int)(8191 - (j + 3)); k64 = k64 > o ? k64 : o;
    }

#pragma unroll
    for (int off = 1; off < 64; off <<= 1) {
      const unsigned long long o = __shfl_xor(k64, off);
      k64 = k64 > o ? k64 : o;
    }
    if (lane == 0) wred[wid] = k64;
    __syncthreads();
    if (wid == 0) {
      unsigned long long v = (lane < 8) ? wred[lane] : 0ull;
#pragma unroll
      for (int off = 4; off; off >>= 1) {
        const unsigned long long o = __shfl_xor(v, off);
        v = v > o ? v : o;
      }
      if (lane == 0) {
        const int fr = 8191 - (int)(v & 0x1FFFu);
        far_sh = fr;
        ob[s] = fr;
      }
    }
    __syncthreads();
    far = far_sh;
  }
}

// ======================= fallback path (small ws) =======================
// R4 geometry (TPB=512, registers held at VGPR~84) + RELAXED store + sleep backoff.

#define R64(M) \
  M(0) M(1) M(2) M(3) M(4) M(5) M(6) M(7) \
  M(8) M(9) M(10) M(11) M(12) M(13) M(14) M(15) \
  M(16) M(17) M(18) M(19) M(20) M(21) M(22) M(23) \
  M(24) M(25) M(26) M(27) M(28) M(29) M(30) M(31) \
  M(32) M(33) M(34) M(35) M(36) M(37) M(38) M(39) \
  M(40) M(41) M(42) M(43) M(44) M(45) M(46) M(47) \
  M(48) M(49) M(50) M(51) M(52) M(53) M(54) M(55) \
  M(56) M(57) M(58) M(59) M(60) M(61) M(62) M(63)

__global__ __attribute__((amdgpu_waves_per_eu(1, 2))) __launch_bounds__(TPB)
void fps_fallback(const float* __restrict__ pts, const float* __restrict__ feat,
                  int* __restrict__ out, unsigned long long* __restrict__ slots) {
  const int blk  = blockIdx.x & (NBLK - 1);
  const int b    = blockIdx.x >> 4;
  const int tid  = threadIdx.x;
  const int lane = tid & 63;
  const int p    = blk * TPB + tid;

  const float* Pp = pts  + (size_t)b * NN * 3 + (size_t)p * 3;
  const float* Fp = feat + (size_t)b * CC * NN + p;

  float fx = Pp[0], fy = Pp[1], fz = Pp[2];
#define DCF(i) float fc##i = Fp[(i) * NN];
  R64(DCF)
#undef DCF
  asm volatile("" : "+v"(fx), "+v"(fy), "+v"(fz));
#define PIN(i) asm volatile("" : "+v"(fc##i));
  R64(PIN)
#undef PIN

  float nrm = 0.f;
  nrm += fx * fx; nrm += fy * fy; nrm += fz * fz;
#define NR(i) nrm += fc##i * fc##i;
  R64(NR)
#undef NR

  __shared__ unsigned long long wred[TPB / 64];
  __shared__ int far_sh;

  if (blk == 0 && tid == 0) out[b * NPT] = 0;

  float mind = 3.0e38f;
  int far = 0;

  for (int s = 1; s < NPT; ++s) {
    const int fu = __builtin_amdgcn_readfirstlane(far);
    const float* Pq = pts  + (size_t)b * NN * 3 + (size_t)fu * 3;
    const float* Fq = feat + (size_t)b * CC * NN + fu;
    const float gx = Pq[0], gy = Pq[1], gz = Pq[2];
#define GL(i) const float gc##i = Fq[(i) * NN];
    R64(GL)
#undef GL
    float nf = 0.f, dot = 0.f;
    nf += gx * gx; nf += gy * gy; nf += gz * gz;
#define NF(i) nf += gc##i * gc##i;
    R64(NF)
#undef NF
    dot += fx * gx; dot += fy * gy; dot += fz * gz;
#define DT(i) dot += fc##i * gc##i;
    R64(DT)
#undef DT
    const float d = (nf + nrm) - 2.0f * dot;
    mind = fminf(mind, d);

    unsigned long long key =
        ((unsigned long long)fkey(mind) << 13) | (unsigned int)(8191 - p);
#pragma unroll
    for (int off = 1; off < 64; off <<= 1) {
      unsigned long long o = __shfl_xor(key, off);
      key = key > o ? key : o;
    }
    if (lane == 0) wred[tid >> 6] = key;
    __syncthreads();

    if (tid < 64) {
      unsigned long long bk = wred[0];
#pragma unroll
      for (int w = 1; w < TPB / 64; ++w) bk = bk > wred[w] ? bk : wred[w];
      unsigned long long* sb = slots + ((size_t)(s & 1) * BB + b) * NBLK;
      if (tid == 0) {
        bk |= ((unsigned long long)s << 45);
        __hip_atomic_store(&sb[blk], bk, __ATOMIC_RELAXED, __HIP_MEMORY_SCOPE_AGENT);
      }
      unsigned long long v = 0;
      for (;;) {
        if (tid < NBLK)
          v = __hip_atomic_load(&sb[tid], __ATOMIC_RELAXED, __HIP_MEMORY_SCOPE_AGENT);
        const bool ok = (tid < NBLK) ? ((v >> 45) == (unsigned long long)s) : true;
        if (__all(ok)) break;
        __builtin_amdgcn_s_sleep(1);
      }
#pragma unroll
      for (int off = 8; off; off >>= 1) {
        unsigned long long o = __shfl_xor(v, off);
        v = v > o ? v : o;
      }
      if (tid == 0) far_sh = 8191 - (int)(v & 0x1FFFu);
    }
    __syncthreads();
    far = far_sh;
    if (blk == 0 && tid == 0) out[b * NPT + s] = far;
  }
}

// ======================= host =======================

extern "C" void kernel_launch(void* const* d_in, const int* in_sizes, int n_in,
                              void* d_out, int out_size, void* d_ws, size_t ws_size,
                              hipStream_t stream) {
  const float* pts  = (const float*)d_in[0];
  const float* feat = (const float*)d_in[1];
  int* out = (int*)d_out;

  const size_t oneD = (size_t)NN * NN * sizeof(float);   // 256 MiB
  if (ws_size >= 2 * oneD) {
    // both matrices fit: build both, then scan both batches concurrently
    float* D = (float*)d_ws;
    for (int b = 0; b < BB; ++b)
      dist_kernel<<<NT * NT, 256, 0, stream>>>(
          pts + (size_t)b * NN * 3, feat + (size_t)b * CC * NN, D + (size_t)b * NN * NN);
    scan_kernel<<<BB, 512, 0, stream>>>(D, (unsigned long long)NN * NN, out, NPT);
  } else if (ws_size >= oneD) {
    // one matrix at a time, sequential per batch
    float* D = (float*)d_ws;
    for (int b = 0; b < BB; ++b) {
      dist_kernel<<<NT * NT, 256, 0, stream>>>(
          pts + (size_t)b * NN * 3, feat + (size_t)b * CC * NN, D);
      scan_kernel<<<1, 512, 0, stream>>>(D, 0, out + (size_t)b * NPT, 0);
    }
  } else {
    unsigned long long* slots = (unsigned long long*)d_ws; // [2][BB][NBLK] = 512 B
    hipMemsetAsync(d_ws, 0, 2 * BB * NBLK * sizeof(unsigned long long), stream);
    void* args[] = {(void*)&pts, (void*)&feat, (void*)&out, (void*)&slots};
    dim3 grid(BB * NBLK), block(TPB);
    hipLaunchCooperativeKernel((void*)fps_fallback, grid, block, args, 0, stream);
  }
}

// Round 7
// 3980.661 us; speedup vs baseline: 2.1835x; 1.0040x over previous
//
#include <hip/hip_runtime.h>

#define BB    2      // batches
#define NN    8192   // points per batch
#define CC    64     // extra feature channels
#define NPT   1024   // npoint
#define NT    128    // 64-wide tiles per dim (8192/64)
#define NBLK  16     // fallback: blocks per batch
#define TPB   512    // fallback: threads per block (1 point per thread)

// monotonic order-preserving key for f32 (handles negatives)
__device__ __forceinline__ unsigned int fkey(float v) {
  unsigned int u = __float_as_uint(v);
  return (u & 0x80000000u) ? ~u : (u | 0x80000000u);
}

// ======================= D-path: dist build (per batch) =======================
// D[i][j] = n_i + n_j - 2*dot(A_i,A_j); norms and dots all accumulated by
// ascending-k fmaf chains over identical tile values -> D[i][i] == 0 bit-exactly,
// and values bit-match the (absmax=0-verified) fallback formula.
__global__ __launch_bounds__(256) void dist_kernel(
    const float* __restrict__ Pb,    // (N,3) for this batch
    const float* __restrict__ Fb,    // (C,N) for this batch
    float* __restrict__ Db) {        // (N,N) out
  __shared__ __align__(16) float Ai[67][64];
  __shared__ __align__(16) float Aj[67][64];
  __shared__ float ni_s[64], nj_s[64];
  const int bid = blockIdx.x;
  const int bi  = bid >> 7, bj = bid & (NT - 1);
  const int t   = threadIdx.x;
  const int i0  = bi * 64, j0 = bj * 64;

  for (int idx = t; idx < 67 * 64; idx += 256) {
    const int c = idx >> 6, r = idx & 63;
    float vi, vj;
    if (c < 3) {
      vi = Pb[(size_t)(i0 + r) * 3 + c];
      vj = Pb[(size_t)(j0 + r) * 3 + c];
    } else {
      vi = Fb[(size_t)(c - 3) * NN + i0 + r];
      vj = Fb[(size_t)(c - 3) * NN + j0 + r];
    }
    Ai[c][r] = vi;
    Aj[c][r] = vj;
  }
  __syncthreads();

  // in-tile norms, same ascending-k fmaf order as the dot below
  if (t < 64) {
    float n = 0.f;
#pragma unroll
    for (int k = 0; k < 67; ++k) n = fmaf(Ai[k][t], Ai[k][t], n);
    ni_s[t] = n;
  } else if (t < 128) {
    const int r = t - 64;
    float n = 0.f;
#pragma unroll
    for (int k = 0; k < 67; ++k) n = fmaf(Aj[k][r], Aj[k][r], n);
    nj_s[r] = n;
  }
  __syncthreads();

  const int tx = t & 15, ty = t >> 4;
  float acc[4][4] = {};
  for (int k = 0; k < 67; ++k) {
    const float4 a = *(const float4*)&Ai[k][ty * 4];
    const float4 v = *(const float4*)&Aj[k][tx * 4];
    acc[0][0] = fmaf(a.x, v.x, acc[0][0]); acc[0][1] = fmaf(a.x, v.y, acc[0][1]);
    acc[0][2] = fmaf(a.x, v.z, acc[0][2]); acc[0][3] = fmaf(a.x, v.w, acc[0][3]);
    acc[1][0] = fmaf(a.y, v.x, acc[1][0]); acc[1][1] = fmaf(a.y, v.y, acc[1][1]);
    acc[1][2] = fmaf(a.y, v.z, acc[1][2]); acc[1][3] = fmaf(a.y, v.w, acc[1][3]);
    acc[2][0] = fmaf(a.z, v.x, acc[2][0]); acc[2][1] = fmaf(a.z, v.y, acc[2][1]);
    acc[2][2] = fmaf(a.z, v.z, acc[2][2]); acc[2][3] = fmaf(a.z, v.w, acc[2][3]);
    acc[3][0] = fmaf(a.w, v.x, acc[3][0]); acc[3][1] = fmaf(a.w, v.y, acc[3][1]);
    acc[3][2] = fmaf(a.w, v.z, acc[3][2]); acc[3][3] = fmaf(a.w, v.w, acc[3][3]);
  }

  const float4 nj4 = *(const float4*)&nj_s[tx * 4];
#pragma unroll
  for (int r = 0; r < 4; ++r) {
    const float nir = ni_s[ty * 4 + r];
    float4 w;
    w.x = (nir + nj4.x) - 2.0f * acc[r][0];
    w.y = (nir + nj4.y) - 2.0f * acc[r][1];
    w.z = (nir + nj4.z) - 2.0f * acc[r][2];
    w.w = (nir + nj4.w) - 2.0f * acc[r][3];
    *(float4*)&Db[(size_t)(i0 + ty * 4 + r) * NN + j0 + tx * 4] = w;
  }
}

// ======================= D-path: serial scan =======================
// One block per batch; block-local sync only. Runner-up row prefetch:
// if mind[runner] survives the update, far(s+1)==runner exactly -> its row
// is already in this XCD's L2. Prefetch is a pure hint (no correctness impact).
__global__ __launch_bounds__(512) void scan_kernel(
    const float* __restrict__ D, unsigned long long dstride,
    int* __restrict__ out, int ostride) {
  const int b = blockIdx.x;
  const float* Db = D + (size_t)b * dstride;
  int* ob = out + (size_t)b * ostride;
  const int tid = threadIdx.x, lane = tid & 63, wid = tid >> 6;  // 8 waves
  __shared__ unsigned long long wred[2][8];

  float4 m[4];
#pragma unroll
  for (int k = 0; k < 4; ++k) m[k] = make_float4(3.0e38f, 3.0e38f, 3.0e38f, 3.0e38f);

  if (tid == 0) ob[0] = 0;
  int far = 0, pred = 0;

  for (int s = 1; s < NPT; ++s) {
    const float4* row = (const float4*)(Db + (size_t)far * NN);
    const float*  prw = Db + (size_t)pred * NN;

    // real row loads (critical path) — issue first
    float4 v[4];
#pragma unroll
    for (int k = 0; k < 4; ++k) v[k] = row[tid + 512 * k];
    // prefetch predicted next row: one dword per 16B chunk warms every 64B line
    float pf[4];
#pragma unroll
    for (int k = 0; k < 4; ++k) pf[k] = prw[(size_t)(tid + 512 * k) * 4];

    unsigned long long k64 = 0;
#pragma unroll
    for (int k = 0; k < 4; ++k) {
      m[k].x = fminf(m[k].x, v[k].x);
      m[k].y = fminf(m[k].y, v[k].y);
      m[k].z = fminf(m[k].z, v[k].z);
      m[k].w = fminf(m[k].w, v[k].w);
      const int j = (tid + 512 * k) * 4;
      unsigned long long o;
      o = ((unsigned long long)fkey(m[k].x) << 13) | (unsigned int)(8191 - j);       k64 = k64 > o ? k64 : o;
      o = ((unsigned long long)fkey(m[k].y) << 13) | (unsigned int)(8191 - (j + 1)); k64 = k64 > o ? k64 : o;
      o = ((unsigned long long)fkey(m[k].z) << 13) | (unsigned int)(8191 - (j + 2)); k64 = k64 > o ? k64 : o;
      o = ((unsigned long long)fkey(m[k].w) << 13) | (unsigned int)(8191 - (j + 3)); k64 = k64 > o ? k64 : o;
    }

    // wave argmax
#pragma unroll
    for (int off = 1; off < 64; off <<= 1) {
      const unsigned long long o = __shfl_xor(k64, off);
      k64 = k64 > o ? k64 : o;
    }
    if (lane == 0) wred[s & 1][wid] = k64;
    __syncthreads();   // single barrier; parity buffer prevents WAR next iter

    // every thread reduces the 8 wave keys: winner + runner-up (prefetch hint)
    unsigned long long kmax = 0, krun = 0;
#pragma unroll
    for (int w8 = 0; w8 < 8; ++w8) {
      const unsigned long long kw = wred[s & 1][w8];
      if (kw > kmax) { krun = kmax; kmax = kw; }
      else if (kw > krun) krun = kw;
    }
    far  = 8191 - (int)(kmax & 0x1FFFu);
    pred = 8191 - (int)(krun & 0x1FFFu);   // always in [0, 8191]
    if (tid == 0) ob[s] = far;
    // keep prefetch loads alive (cache-warm only); completes in background
    asm volatile("" :: "v"(pf[0]), "v"(pf[1]), "v"(pf[2]), "v"(pf[3]));
  }
}

// ======================= fallback path (small ws; kept for safety) =======================

#define R64(M) \
  M(0) M(1) M(2) M(3) M(4) M(5) M(6) M(7) \
  M(8) M(9) M(10) M(11) M(12) M(13) M(14) M(15) \
  M(16) M(17) M(18) M(19) M(20) M(21) M(22) M(23) \
  M(24) M(25) M(26) M(27) M(28) M(29) M(30) M(31) \
  M(32) M(33) M(34) M(35) M(36) M(37) M(38) M(39) \
  M(40) M(41) M(42) M(43) M(44) M(45) M(46) M(47) \
  M(48) M(49) M(50) M(51) M(52) M(53) M(54) M(55) \
  M(56) M(57) M(58) M(59) M(60) M(61) M(62) M(63)

__global__ __attribute__((amdgpu_waves_per_eu(1, 2))) __launch_bounds__(TPB)
void fps_fallback(const float* __restrict__ pts, const float* __restrict__ feat,
                  int* __restrict__ out, unsigned long long* __restrict__ slots) {
  const int blk  = blockIdx.x & (NBLK - 1);
  const int b    = blockIdx.x >> 4;
  const int tid  = threadIdx.x;
  const int lane = tid & 63;
  const int p    = blk * TPB + tid;

  const float* Pp = pts  + (size_t)b * NN * 3 + (size_t)p * 3;
  const float* Fp = feat + (size_t)b * CC * NN + p;

  float fx = Pp[0], fy = Pp[1], fz = Pp[2];
#define DCF(i) float fc##i = Fp[(i) * NN];
  R64(DCF)
#undef DCF
  asm volatile("" : "+v"(fx), "+v"(fy), "+v"(fz));
#define PIN(i) asm volatile("" : "+v"(fc##i));
  R64(PIN)
#undef PIN

  float nrm = 0.f;
  nrm += fx * fx; nrm += fy * fy; nrm += fz * fz;
#define NR(i) nrm += fc##i * fc##i;
  R64(NR)
#undef NR

  __shared__ unsigned long long wred[TPB / 64];
  __shared__ int far_sh;

  if (blk == 0 && tid == 0) out[b * NPT] = 0;

  float mind = 3.0e38f;
  int far = 0;

  for (int s = 1; s < NPT; ++s) {
    const int fu = __builtin_amdgcn_readfirstlane(far);
    const float* Pq = pts  + (size_t)b * NN * 3 + (size_t)fu * 3;
    const float* Fq = feat + (size_t)b * CC * NN + fu;
    const float gx = Pq[0], gy = Pq[1], gz = Pq[2];
#define GL(i) const float gc##i = Fq[(i) * NN];
    R64(GL)
#undef GL
    float nf = 0.f, dot = 0.f;
    nf += gx * gx; nf += gy * gy; nf += gz * gz;
#define NF(i) nf += gc##i * gc##i;
    R64(NF)
#undef NF
    dot += fx * gx; dot += fy * gy; dot += fz * gz;
#define DT(i) dot += fc##i * gc##i;
    R64(DT)
#undef DT
    const float d = (nf + nrm) - 2.0f * dot;
    mind = fminf(mind, d);

    unsigned long long key =
        ((unsigned long long)fkey(mind) << 13) | (unsigned int)(8191 - p);
#pragma unroll
    for (int off = 1; off < 64; off <<= 1) {
      unsigned long long o = __shfl_xor(key, off);
      key = key > o ? key : o;
    }
    if (lane == 0) wred[tid >> 6] = key;
    __syncthreads();

    if (tid < 64) {
      unsigned long long bk = wred[0];
#pragma unroll
      for (int w = 1; w < TPB / 64; ++w) bk = bk > wred[w] ? bk : wred[w];
      unsigned long long* sb = slots + ((size_t)(s & 1) * BB + b) * NBLK;
      if (tid == 0) {
        bk |= ((unsigned long long)s << 45);
        __hip_atomic_store(&sb[blk], bk, __ATOMIC_RELAXED, __HIP_MEMORY_SCOPE_AGENT);
      }
      unsigned long long v = 0;
      for (;;) {
        if (tid < NBLK)
          v = __hip_atomic_load(&sb[tid], __ATOMIC_RELAXED, __HIP_MEMORY_SCOPE_AGENT);
        const bool ok = (tid < NBLK) ? ((v >> 45) == (unsigned long long)s) : true;
        if (__all(ok)) break;
        __builtin_amdgcn_s_sleep(1);
      }
#pragma unroll
      for (int off = 8; off; off >>= 1) {
        unsigned long long o = __shfl_xor(v, off);
        v = v > o ? v : o;
      }
      if (tid == 0) far_sh = 8191 - (int)(v & 0x1FFFu);
    }
    __syncthreads();
    far = far_sh;
    if (blk == 0 && tid == 0) out[b * NPT + s] = far;
  }
}

// ======================= host =======================

extern "C" void kernel_launch(void* const* d_in, const int* in_sizes, int n_in,
                              void* d_out, int out_size, void* d_ws, size_t ws_size,
                              hipStream_t stream) {
  const float* pts  = (const float*)d_in[0];
  const float* feat = (const float*)d_in[1];
  int* out = (int*)d_out;

  const size_t oneD = (size_t)NN * NN * sizeof(float);   // 256 MiB
  if (ws_size >= 2 * oneD) {
    // both matrices fit: build both, then scan both batches concurrently
    float* D = (float*)d_ws;
    for (int b = 0; b < BB; ++b)
      dist_kernel<<<NT * NT, 256, 0, stream>>>(
          pts + (size_t)b * NN * 3, feat + (size_t)b * CC * NN, D + (size_t)b * NN * NN);
    scan_kernel<<<BB, 512, 0, stream>>>(D, (unsigned long long)NN * NN, out, NPT);
  } else if (ws_size >= oneD) {
    // one matrix at a time, sequential per batch
    float* D = (float*)d_ws;
    for (int b = 0; b < BB; ++b) {
      dist_kernel<<<NT * NT, 256, 0, stream>>>(
          pts + (size_t)b * NN * 3, feat + (size_t)b * CC * NN, D);
      scan_kernel<<<1, 512, 0, stream>>>(D, 0, out + (size_t)b * NPT, 0);
    }
  } else {
    unsigned long long* slots = (unsigned long long*)d_ws; // [2][BB][NBLK] = 512 B
    hipMemsetAsync(d_ws, 0, 2 * BB * NBLK * sizeof(unsigned long long), stream);
    void* args[] = {(void*)&pts, (void*)&feat, (void*)&out, (void*)&slots};
    dim3 grid(BB * NBLK), block(TPB);
    hipLaunchCooperativeKernel((void*)fps_fallback, grid, block, args, 0, stream);
  }
}

// Round 8
// 3333.189 us; speedup vs baseline: 2.6076x; 1.1942x over previous
//
#include <hip/hip_runtime.h>

#define BB    2      // batches
#define NN    8192   // points per batch
#define CC    64     // extra feature channels
#define NPT   1024   // npoint
#define NT    128    // 64-wide tiles per dim (8192/64)
#define NBLK  16     // fallback: blocks per batch
#define TPB   512    // fallback: threads per block (1 point per thread)

// monotonic order-preserving key for f32 (handles negatives)
__device__ __forceinline__ unsigned int fkey(float v) {
  unsigned int u = __float_as_uint(v);
  return (u & 0x80000000u) ? ~u : (u | 0x80000000u);
}

// wave64 max-reduce of u32 via DPP (rocPRIM pattern); result valid in lane 63,
// returned uniform via readlane. ~150 cy vs ~600 cy for bpermute-based shuffles.
__device__ __forceinline__ unsigned wave_max_u32(unsigned x) {
  int v = (int)x, t;
  t = __builtin_amdgcn_update_dpp(v, v, 0x111, 0xf, 0xf, false);  // row_shr:1
  v = ((unsigned)t > (unsigned)v) ? t : v;
  t = __builtin_amdgcn_update_dpp(v, v, 0x112, 0xf, 0xf, false);  // row_shr:2
  v = ((unsigned)t > (unsigned)v) ? t : v;
  t = __builtin_amdgcn_update_dpp(v, v, 0x114, 0xf, 0xf, false);  // row_shr:4
  v = ((unsigned)t > (unsigned)v) ? t : v;
  t = __builtin_amdgcn_update_dpp(v, v, 0x118, 0xf, 0xf, false);  // row_shr:8
  v = ((unsigned)t > (unsigned)v) ? t : v;
  t = __builtin_amdgcn_update_dpp(v, v, 0x142, 0xa, 0xf, false);  // row_bcast:15
  v = ((unsigned)t > (unsigned)v) ? t : v;
  t = __builtin_amdgcn_update_dpp(v, v, 0x143, 0xc, 0xf, false);  // row_bcast:31
  v = ((unsigned)t > (unsigned)v) ? t : v;
  return (unsigned)__builtin_amdgcn_readlane(v, 63);
}

// ======================= D-path: dist build (per batch) =======================
// D[i][j] = n_i + n_j - 2*dot(A_i,A_j); norms and dots all accumulated by
// ascending-k fmaf chains over identical tile values -> D[i][i] == 0 bit-exactly,
// and values bit-match the (absmax=0-verified) fallback formula.
__global__ __launch_bounds__(256) void dist_kernel(
    const float* __restrict__ Pb,    // (N,3) for this batch
    const float* __restrict__ Fb,    // (C,N) for this batch
    float* __restrict__ Db) {        // (N,N) out
  __shared__ __align__(16) float Ai[67][64];
  __shared__ __align__(16) float Aj[67][64];
  __shared__ float ni_s[64], nj_s[64];
  const int bid = blockIdx.x;
  const int bi  = bid >> 7, bj = bid & (NT - 1);
  const int t   = threadIdx.x;
  const int i0  = bi * 64, j0 = bj * 64;

  for (int idx = t; idx < 67 * 64; idx += 256) {
    const int c = idx >> 6, r = idx & 63;
    float vi, vj;
    if (c < 3) {
      vi = Pb[(size_t)(i0 + r) * 3 + c];
      vj = Pb[(size_t)(j0 + r) * 3 + c];
    } else {
      vi = Fb[(size_t)(c - 3) * NN + i0 + r];
      vj = Fb[(size_t)(c - 3) * NN + j0 + r];
    }
    Ai[c][r] = vi;
    Aj[c][r] = vj;
  }
  __syncthreads();

  if (t < 64) {
    float n = 0.f;
#pragma unroll
    for (int k = 0; k < 67; ++k) n = fmaf(Ai[k][t], Ai[k][t], n);
    ni_s[t] = n;
  } else if (t < 128) {
    const int r = t - 64;
    float n = 0.f;
#pragma unroll
    for (int k = 0; k < 67; ++k) n = fmaf(Aj[k][r], Aj[k][r], n);
    nj_s[r] = n;
  }
  __syncthreads();

  const int tx = t & 15, ty = t >> 4;
  float acc[4][4] = {};
  for (int k = 0; k < 67; ++k) {
    const float4 a = *(const float4*)&Ai[k][ty * 4];
    const float4 v = *(const float4*)&Aj[k][tx * 4];
    acc[0][0] = fmaf(a.x, v.x, acc[0][0]); acc[0][1] = fmaf(a.x, v.y, acc[0][1]);
    acc[0][2] = fmaf(a.x, v.z, acc[0][2]); acc[0][3] = fmaf(a.x, v.w, acc[0][3]);
    acc[1][0] = fmaf(a.y, v.x, acc[1][0]); acc[1][1] = fmaf(a.y, v.y, acc[1][1]);
    acc[1][2] = fmaf(a.y, v.z, acc[1][2]); acc[1][3] = fmaf(a.y, v.w, acc[1][3]);
    acc[2][0] = fmaf(a.z, v.x, acc[2][0]); acc[2][1] = fmaf(a.z, v.y, acc[2][1]);
    acc[2][2] = fmaf(a.z, v.z, acc[2][2]); acc[2][3] = fmaf(a.z, v.w, acc[2][3]);
    acc[3][0] = fmaf(a.w, v.x, acc[3][0]); acc[3][1] = fmaf(a.w, v.y, acc[3][1]);
    acc[3][2] = fmaf(a.w, v.z, acc[3][2]); acc[3][3] = fmaf(a.w, v.w, acc[3][3]);
  }

  const float4 nj4 = *(const float4*)&nj_s[tx * 4];
#pragma unroll
  for (int r = 0; r < 4; ++r) {
    const float nir = ni_s[ty * 4 + r];
    float4 w;
    w.x = (nir + nj4.x) - 2.0f * acc[r][0];
    w.y = (nir + nj4.y) - 2.0f * acc[r][1];
    w.z = (nir + nj4.z) - 2.0f * acc[r][2];
    w.w = (nir + nj4.w) - 2.0f * acc[r][3];
    *(float4*)&Db[(size_t)(i0 + ty * 4 + r) * NN + j0 + tx * 4] = w;
  }
}

// ======================= D-path: serial scan =======================
// One block (1024 thr, 16 waves, 1 CU) per batch; block-local sync only.
// Per step: 32KB row read -> elementwise fmin -> per-thread (best,bj) ->
// DPP wave reduce (value, then tie) -> 16-entry LDS final -> far.
__global__ __launch_bounds__(1024) void scan_kernel(
    const float* __restrict__ D, unsigned long long dstride,
    int* __restrict__ out, int ostride) {
  const int b = blockIdx.x;
  const float* Db = D + (size_t)b * dstride;
  int* ob = out + (size_t)b * ostride;
  const int tid = threadIdx.x, lane = tid & 63, wid = tid >> 6;  // 16 waves
  __shared__ unsigned long long wred[2][16];

  float4 m0 = make_float4(3.0e38f, 3.0e38f, 3.0e38f, 3.0e38f);
  float4 m1 = m0;
  if (tid == 0) ob[0] = 0;
  int far = 0;

  for (int s = 1; s < NPT; ++s) {
    const float4* row = (const float4*)(Db + (size_t)far * NN);
    const float4 v0 = row[tid];
    const float4 v1 = row[tid + 1024];

    m0.x = fminf(m0.x, v0.x); m0.y = fminf(m0.y, v0.y);
    m0.z = fminf(m0.z, v0.z); m0.w = fminf(m0.w, v0.w);
    m1.x = fminf(m1.x, v1.x); m1.y = fminf(m1.y, v1.y);
    m1.z = fminf(m1.z, v1.z); m1.w = fminf(m1.w, v1.w);

    // per-thread argmax, strict > over ascending j -> lowest-index tie-break
    const int j0 = tid * 4, j1 = 4096 + tid * 4;
    float best = m0.x; int bj = j0;
    if (m0.y > best) { best = m0.y; bj = j0 + 1; }
    if (m0.z > best) { best = m0.z; bj = j0 + 2; }
    if (m0.w > best) { best = m0.w; bj = j0 + 3; }
    if (m1.x > best) { best = m1.x; bj = j1; }
    if (m1.y > best) { best = m1.y; bj = j1 + 1; }
    if (m1.z > best) { best = m1.z; bj = j1 + 2; }
    if (m1.w > best) { best = m1.w; bj = j1 + 3; }

    // wave reduce: value first, then lowest-j among value winners
    const unsigned fk = fkey(best);
    const unsigned wmax = wave_max_u32(fk);
    const unsigned cand = (fk == wmax) ? (8191u - (unsigned)bj) : 0u;
    const unsigned wtie = wave_max_u32(cand);

    if (lane == 0)
      wred[s & 1][wid] = ((unsigned long long)wmax << 32) | wtie;
    __syncthreads();   // single barrier; parity buffer prevents WAR next iter

    // all threads reduce the 16 wave keys (u64 max = max value, then lowest j)
    unsigned long long g0 = wred[s & 1][0],  g1 = wred[s & 1][1];
    unsigned long long g2 = wred[s & 1][2],  g3 = wred[s & 1][3];
    unsigned long long g4 = wred[s & 1][4],  g5 = wred[s & 1][5];
    unsigned long long g6 = wred[s & 1][6],  g7 = wred[s & 1][7];
    unsigned long long g8 = wred[s & 1][8],  g9 = wred[s & 1][9];
    unsigned long long ga = wred[s & 1][10], gb = wred[s & 1][11];
    unsigned long long gc = wred[s & 1][12], gd = wred[s & 1][13];
    unsigned long long ge = wred[s & 1][14], gf = wred[s & 1][15];
    g0 = g0 > g1 ? g0 : g1;  g2 = g2 > g3 ? g2 : g3;
    g4 = g4 > g5 ? g4 : g5;  g6 = g6 > g7 ? g6 : g7;
    g8 = g8 > g9 ? g8 : g9;  ga = ga > gb ? ga : gb;
    gc = gc > gd ? gc : gd;  ge = ge > gf ? ge : gf;
    g0 = g0 > g2 ? g0 : g2;  g4 = g4 > g6 ? g4 : g6;
    g8 = g8 > ga ? g8 : ga;  gc = gc > ge ? gc : ge;
    g0 = g0 > g4 ? g0 : g4;  g8 = g8 > gc ? g8 : gc;
    g0 = g0 > g8 ? g0 : g8;

    far = 8191 - (int)(g0 & 0x1FFFu);
    if (tid == 0) ob[s] = far;
  }
}

// ======================= fallback path (small ws; kept for safety) =======================

#define R64(M) \
  M(0) M(1) M(2) M(3) M(4) M(5) M(6) M(7) \
  M(8) M(9) M(10) M(11) M(12) M(13) M(14) M(15) \
  M(16) M(17) M(18) M(19) M(20) M(21) M(22) M(23) \
  M(24) M(25) M(26) M(27) M(28) M(29) M(30) M(31) \
  M(32) M(33) M(34) M(35) M(36) M(37) M(38) M(39) \
  M(40) M(41) M(42) M(43) M(44) M(45) M(46) M(47) \
  M(48) M(49) M(50) M(51) M(52) M(53) M(54) M(55) \
  M(56) M(57) M(58) M(59) M(60) M(61) M(62) M(63)

__global__ __attribute__((amdgpu_waves_per_eu(1, 2))) __launch_bounds__(TPB)
void fps_fallback(const float* __restrict__ pts, const float* __restrict__ feat,
                  int* __restrict__ out, unsigned long long* __restrict__ slots) {
  const int blk  = blockIdx.x & (NBLK - 1);
  const int b    = blockIdx.x >> 4;
  const int tid  = threadIdx.x;
  const int lane = tid & 63;
  const int p    = blk * TPB + tid;

  const float* Pp = pts  + (size_t)b * NN * 3 + (size_t)p * 3;
  const float* Fp = feat + (size_t)b * CC * NN + p;

  float fx = Pp[0], fy = Pp[1], fz = Pp[2];
#define DCF(i) float fc##i = Fp[(i) * NN];
  R64(DCF)
#undef DCF
  asm volatile("" : "+v"(fx), "+v"(fy), "+v"(fz));
#define PIN(i) asm volatile("" : "+v"(fc##i));
  R64(PIN)
#undef PIN

  float nrm = 0.f;
  nrm += fx * fx; nrm += fy * fy; nrm += fz * fz;
#define NR(i) nrm += fc##i * fc##i;
  R64(NR)
#undef NR

  __shared__ unsigned long long wred[TPB / 64];
  __shared__ int far_sh;

  if (blk == 0 && tid == 0) out[b * NPT] = 0;

  float mind = 3.0e38f;
  int far = 0;

  for (int s = 1; s < NPT; ++s) {
    const int fu = __builtin_amdgcn_readfirstlane(far);
    const float* Pq = pts  + (size_t)b * NN * 3 + (size_t)fu * 3;
    const float* Fq = feat + (size_t)b * CC * NN + fu;
    const float gx = Pq[0], gy = Pq[1], gz = Pq[2];
#define GL(i) const float gc##i = Fq[(i) * NN];
    R64(GL)
#undef GL
    float nf = 0.f, dot = 0.f;
    nf += gx * gx; nf += gy * gy; nf += gz * gz;
#define NF(i) nf += gc##i * gc##i;
    R64(NF)
#undef NF
    dot += fx * gx; dot += fy * gy; dot += fz * gz;
#define DT(i) dot += fc##i * gc##i;
    R64(DT)
#undef DT
    const float d = (nf + nrm) - 2.0f * dot;
    mind = fminf(mind, d);

    unsigned long long key =
        ((unsigned long long)fkey(mind) << 13) | (unsigned int)(8191 - p);
#pragma unroll
    for (int off = 1; off < 64; off <<= 1) {
      unsigned long long o = __shfl_xor(key, off);
      key = key > o ? key : o;
    }
    if (lane == 0) wred[tid >> 6] = key;
    __syncthreads();

    if (tid < 64) {
      unsigned long long bk = wred[0];
#pragma unroll
      for (int w = 1; w < TPB / 64; ++w) bk = bk > wred[w] ? bk : wred[w];
      unsigned long long* sb = slots + ((size_t)(s & 1) * BB + b) * NBLK;
      if (tid == 0) {
        bk |= ((unsigned long long)s << 45);
        __hip_atomic_store(&sb[blk], bk, __ATOMIC_RELAXED, __HIP_MEMORY_SCOPE_AGENT);
      }
      unsigned long long v = 0;
      for (;;) {
        if (tid < NBLK)
          v = __hip_atomic_load(&sb[tid], __ATOMIC_RELAXED, __HIP_MEMORY_SCOPE_AGENT);
        const bool ok = (tid < NBLK) ? ((v >> 45) == (unsigned long long)s) : true;
        if (__all(ok)) break;
        __builtin_amdgcn_s_sleep(1);
      }
#pragma unroll
      for (int off = 8; off; off >>= 1) {
        unsigned long long o = __shfl_xor(v, off);
        v = v > o ? v : o;
      }
      if (tid == 0) far_sh = 8191 - (int)(v & 0x1FFFu);
    }
    __syncthreads();
    far = far_sh;
    if (blk == 0 && tid == 0) out[b * NPT + s] = far;
  }
}

// ======================= host =======================

extern "C" void kernel_launch(void* const* d_in, const int* in_sizes, int n_in,
                              void* d_out, int out_size, void* d_ws, size_t ws_size,
                              hipStream_t stream) {
  const float* pts  = (const float*)d_in[0];
  const float* feat = (const float*)d_in[1];
  int* out = (int*)d_out;

  const size_t oneD = (size_t)NN * NN * sizeof(float);   // 256 MiB
  if (ws_size >= 2 * oneD) {
    float* D = (float*)d_ws;
    for (int b = 0; b < BB; ++b)
      dist_kernel<<<NT * NT, 256, 0, stream>>>(
          pts + (size_t)b * NN * 3, feat + (size_t)b * CC * NN, D + (size_t)b * NN * NN);
    scan_kernel<<<BB, 1024, 0, stream>>>(D, (unsigned long long)NN * NN, out, NPT);
  } else if (ws_size >= oneD) {
    float* D = (float*)d_ws;
    for (int b = 0; b < BB; ++b) {
      dist_kernel<<<NT * NT, 256, 0, stream>>>(
          pts + (size_t)b * NN * 3, feat + (size_t)b * CC * NN, D);
      scan_kernel<<<1, 1024, 0, stream>>>(D, 0, out + (size_t)b * NPT, 0);
    }
  } else {
    unsigned long long* slots = (unsigned long long*)d_ws; // [2][BB][NBLK] = 512 B
    hipMemsetAsync(d_ws, 0, 2 * BB * NBLK * sizeof(unsigned long long), stream);
    void* args[] = {(void*)&pts, (void*)&feat, (void*)&out, (void*)&slots};
    dim3 grid(BB * NBLK), block(TPB);
    hipLaunchCooperativeKernel((void*)fps_fallback, grid, block, args, 0, stream);
  }
}

// Round 9
// 2190.905 us; speedup vs baseline: 3.9672x; 1.5214x over previous
//
#include <hip/hip_runtime.h>

#define BB    2      // batches
#define NN    8192   // points per batch
#define CC    64     // extra feature channels
#define NPT   1024   // npoint
#define NT    128    // 64-wide tiles per dim (8192/64)
#define NBLK  16     // fallback: blocks per batch
#define TPB   512    // fallback: threads per block (1 point per thread)

// monotonic order-preserving key for f32 (handles negatives)
__device__ __forceinline__ unsigned int fkey(float v) {
  unsigned int u = __float_as_uint(v);
  return (u & 0x80000000u) ? ~u : (u | 0x80000000u);
}

// wave64 max-reduce of u32 via DPP (rocPRIM pattern); result broadcast via
// readlane(63). Prefix-max over rows (shr 1/2/4/8) then row_bcast 15/31.
__device__ __forceinline__ unsigned wave_max_u32(unsigned x) {
  int v = (int)x, t;
  t = __builtin_amdgcn_update_dpp(v, v, 0x111, 0xf, 0xf, false);  // row_shr:1
  v = ((unsigned)t > (unsigned)v) ? t : v;
  t = __builtin_amdgcn_update_dpp(v, v, 0x112, 0xf, 0xf, false);  // row_shr:2
  v = ((unsigned)t > (unsigned)v) ? t : v;
  t = __builtin_amdgcn_update_dpp(v, v, 0x114, 0xf, 0xf, false);  // row_shr:4
  v = ((unsigned)t > (unsigned)v) ? t : v;
  t = __builtin_amdgcn_update_dpp(v, v, 0x118, 0xf, 0xf, false);  // row_shr:8
  v = ((unsigned)t > (unsigned)v) ? t : v;
  t = __builtin_amdgcn_update_dpp(v, v, 0x142, 0xa, 0xf, false);  // row_bcast:15
  v = ((unsigned)t > (unsigned)v) ? t : v;
  t = __builtin_amdgcn_update_dpp(v, v, 0x143, 0xc, 0xf, false);  // row_bcast:31
  v = ((unsigned)t > (unsigned)v) ? t : v;
  return (unsigned)__builtin_amdgcn_readlane(v, 63);
}

// ======================= D-path: dist build (per batch) =======================
// D[i][j] = n_i + n_j - 2*dot(A_i,A_j); norms and dots all accumulated by
// ascending-k fmaf chains over identical tile values -> D[i][i] == 0 bit-exactly,
// and values bit-match the (absmax=0-verified) fallback formula.
__global__ __launch_bounds__(256) void dist_kernel(
    const float* __restrict__ Pb,    // (N,3) for this batch
    const float* __restrict__ Fb,    // (C,N) for this batch
    float* __restrict__ Db) {        // (N,N) out
  __shared__ __align__(16) float Ai[67][64];
  __shared__ __align__(16) float Aj[67][64];
  __shared__ float ni_s[64], nj_s[64];
  const int bid = blockIdx.x;
  const int bi  = bid >> 7, bj = bid & (NT - 1);
  const int t   = threadIdx.x;
  const int i0  = bi * 64, j0 = bj * 64;

  for (int idx = t; idx < 67 * 64; idx += 256) {
    const int c = idx >> 6, r = idx & 63;
    float vi, vj;
    if (c < 3) {
      vi = Pb[(size_t)(i0 + r) * 3 + c];
      vj = Pb[(size_t)(j0 + r) * 3 + c];
    } else {
      vi = Fb[(size_t)(c - 3) * NN + i0 + r];
      vj = Fb[(size_t)(c - 3) * NN + j0 + r];
    }
    Ai[c][r] = vi;
    Aj[c][r] = vj;
  }
  __syncthreads();

  if (t < 64) {
    float n = 0.f;
#pragma unroll
    for (int k = 0; k < 67; ++k) n = fmaf(Ai[k][t], Ai[k][t], n);
    ni_s[t] = n;
  } else if (t < 128) {
    const int r = t - 64;
    float n = 0.f;
#pragma unroll
    for (int k = 0; k < 67; ++k) n = fmaf(Aj[k][r], Aj[k][r], n);
    nj_s[r] = n;
  }
  __syncthreads();

  const int tx = t & 15, ty = t >> 4;
  float acc[4][4] = {};
  for (int k = 0; k < 67; ++k) {
    const float4 a = *(const float4*)&Ai[k][ty * 4];
    const float4 v = *(const float4*)&Aj[k][tx * 4];
    acc[0][0] = fmaf(a.x, v.x, acc[0][0]); acc[0][1] = fmaf(a.x, v.y, acc[0][1]);
    acc[0][2] = fmaf(a.x, v.z, acc[0][2]); acc[0][3] = fmaf(a.x, v.w, acc[0][3]);
    acc[1][0] = fmaf(a.y, v.x, acc[1][0]); acc[1][1] = fmaf(a.y, v.y, acc[1][1]);
    acc[1][2] = fmaf(a.y, v.z, acc[1][2]); acc[1][3] = fmaf(a.y, v.w, acc[1][3]);
    acc[2][0] = fmaf(a.z, v.x, acc[2][0]); acc[2][1] = fmaf(a.z, v.y, acc[2][1]);
    acc[2][2] = fmaf(a.z, v.z, acc[2][2]); acc[2][3] = fmaf(a.z, v.w, acc[2][3]);
    acc[3][0] = fmaf(a.w, v.x, acc[3][0]); acc[3][1] = fmaf(a.w, v.y, acc[3][1]);
    acc[3][2] = fmaf(a.w, v.z, acc[3][2]); acc[3][3] = fmaf(a.w, v.w, acc[3][3]);
  }

  const float4 nj4 = *(const float4*)&nj_s[tx * 4];
#pragma unroll
  for (int r = 0; r < 4; ++r) {
    const float nir = ni_s[ty * 4 + r];
    float4 w;
    w.x = (nir + nj4.x) - 2.0f * acc[r][0];
    w.y = (nir + nj4.y) - 2.0f * acc[r][1];
    w.z = (nir + nj4.z) - 2.0f * acc[r][2];
    w.w = (nir + nj4.w) - 2.0f * acc[r][3];
    *(float4*)&Db[(size_t)(i0 + ty * 4 + r) * NN + j0 + tx * 4] = w;
  }
}

// ======================= D-path: serial scan =======================
// One block (512 thr, 8 waves, 1 CU) per batch; block-local sync only.
// Per step: 32KB row read (16 elems/thread) -> fmin -> per-thread argmax ->
// DPP wave reduce -> ONE ds_max_u64 per wave into a 3-slot rotating LDS cell
// (race-free with a single barrier: slot s%3 written before barrier(s), read
// after; slot (s+1)%3 reset in this window, next used after barrier(s)).
__global__ __launch_bounds__(512) void scan_kernel(
    const float* __restrict__ D, unsigned long long dstride,
    int* __restrict__ out, int ostride) {
  const int b = blockIdx.x;
  const float* Db = D + (size_t)b * dstride;
  int* ob = out + (size_t)b * ostride;
  const int tid = threadIdx.x, lane = tid & 63;
  __shared__ unsigned long long slot[3];
  if (tid < 3) slot[tid] = 0ull;
  __syncthreads();

  float4 m[4];
#pragma unroll
  for (int k = 0; k < 4; ++k) m[k] = make_float4(3.0e38f, 3.0e38f, 3.0e38f, 3.0e38f);

  if (tid == 0) ob[0] = 0;
  int far = 0;

  for (int s = 1; s < NPT; ++s) {
    const float4* row4 = (const float4*)(Db + (size_t)far * NN);
    float4 v[4];
#pragma unroll
    for (int k = 0; k < 4; ++k) v[k] = row4[tid + 512 * k];
#pragma unroll
    for (int k = 0; k < 4; ++k) {
      m[k].x = fminf(m[k].x, v[k].x);
      m[k].y = fminf(m[k].y, v[k].y);
      m[k].z = fminf(m[k].z, v[k].z);
      m[k].w = fminf(m[k].w, v[k].w);
    }

    // per-thread argmax, strict > over ascending j -> lowest-index tie-break
    const int j0 = tid * 4;
    float best = m[0].x; int bj = j0;
#define CHK(val, jj) if ((val) > best) { best = (val); bj = (jj); }
    CHK(m[0].y, j0 + 1) CHK(m[0].z, j0 + 2) CHK(m[0].w, j0 + 3)
    CHK(m[1].x, j0 + 2048) CHK(m[1].y, j0 + 2049) CHK(m[1].z, j0 + 2050) CHK(m[1].w, j0 + 2051)
    CHK(m[2].x, j0 + 4096) CHK(m[2].y, j0 + 4097) CHK(m[2].z, j0 + 4098) CHK(m[2].w, j0 + 4099)
    CHK(m[3].x, j0 + 6144) CHK(m[3].y, j0 + 6145) CHK(m[3].z, j0 + 6146) CHK(m[3].w, j0 + 6147)
#undef CHK

    // wave reduce: value first, then lowest-j among value winners
    const unsigned fk   = fkey(best);
    const unsigned wmax = wave_max_u32(fk);
    const unsigned cand = (fk == wmax) ? (8191u - (unsigned)bj) : 0u;
    const unsigned wtie = wave_max_u32(cand);

    // one LDS atomic per wave; rotate slots mod 3; reset next slot this window
    if (lane == 0)
      atomicMax(&slot[s % 3], ((unsigned long long)wmax << 32) | wtie);
    if (tid == 0) slot[(s + 1) % 3] = 0ull;
    __syncthreads();

    const unsigned long long g = slot[s % 3];
    far = 8191 - (int)(g & 0x1FFFu);
    if (tid == 0) ob[s] = far;
  }
}

// ======================= fallback path (small ws; kept for safety) =======================

#define R64(M) \
  M(0) M(1) M(2) M(3) M(4) M(5) M(6) M(7) \
  M(8) M(9) M(10) M(11) M(12) M(13) M(14) M(15) \
  M(16) M(17) M(18) M(19) M(20) M(21) M(22) M(23) \
  M(24) M(25) M(26) M(27) M(28) M(29) M(30) M(31) \
  M(32) M(33) M(34) M(35) M(36) M(37) M(38) M(39) \
  M(40) M(41) M(42) M(43) M(44) M(45) M(46) M(47) \
  M(48) M(49) M(50) M(51) M(52) M(53) M(54) M(55) \
  M(56) M(57) M(58) M(59) M(60) M(61) M(62) M(63)

__global__ __attribute__((amdgpu_waves_per_eu(1, 2))) __launch_bounds__(TPB)
void fps_fallback(const float* __restrict__ pts, const float* __restrict__ feat,
                  int* __restrict__ out, unsigned long long* __restrict__ slots) {
  const int blk  = blockIdx.x & (NBLK - 1);
  const int b    = blockIdx.x >> 4;
  const int tid  = threadIdx.x;
  const int lane = tid & 63;
  const int p    = blk * TPB + tid;

  const float* Pp = pts  + (size_t)b * NN * 3 + (size_t)p * 3;
  const float* Fp = feat + (size_t)b * CC * NN + p;

  float fx = Pp[0], fy = Pp[1], fz = Pp[2];
#define DCF(i) float fc##i = Fp[(i) * NN];
  R64(DCF)
#undef DCF
  asm volatile("" : "+v"(fx), "+v"(fy), "+v"(fz));
#define PIN(i) asm volatile("" : "+v"(fc##i));
  R64(PIN)
#undef PIN

  float nrm = 0.f;
  nrm += fx * fx; nrm += fy * fy; nrm += fz * fz;
#define NR(i) nrm += fc##i * fc##i;
  R64(NR)
#undef NR

  __shared__ unsigned long long wred[TPB / 64];
  __shared__ int far_sh;

  if (blk == 0 && tid == 0) out[b * NPT] = 0;

  float mind = 3.0e38f;
  int far = 0;

  for (int s = 1; s < NPT; ++s) {
    const int fu = __builtin_amdgcn_readfirstlane(far);
    const float* Pq = pts  + (size_t)b * NN * 3 + (size_t)fu * 3;
    const float* Fq = feat + (size_t)b * CC * NN + fu;
    const float gx = Pq[0], gy = Pq[1], gz = Pq[2];
#define GL(i) const float gc##i = Fq[(i) * NN];
    R64(GL)
#undef GL
    float nf = 0.f, dot = 0.f;
    nf += gx * gx; nf += gy * gy; nf += gz * gz;
#define NF(i) nf += gc##i * gc##i;
    R64(NF)
#undef NF
    dot += fx * gx; dot += fy * gy; dot += fz * gz;
#define DT(i) dot += fc##i * gc##i;
    R64(DT)
#undef DT
    const float d = (nf + nrm) - 2.0f * dot;
    mind = fminf(mind, d);

    unsigned long long key =
        ((unsigned long long)fkey(mind) << 13) | (unsigned int)(8191 - p);
#pragma unroll
    for (int off = 1; off < 64; off <<= 1) {
      unsigned long long o = __shfl_xor(key, off);
      key = key > o ? key : o;
    }
    if (lane == 0) wred[tid >> 6] = key;
    __syncthreads();

    if (tid < 64) {
      unsigned long long bk = wred[0];
#pragma unroll
      for (int w = 1; w < TPB / 64; ++w) bk = bk > wred[w] ? bk : wred[w];
      unsigned long long* sb = slots + ((size_t)(s & 1) * BB + b) * NBLK;
      if (tid == 0) {
        bk |= ((unsigned long long)s << 45);
        __hip_atomic_store(&sb[blk], bk, __ATOMIC_RELAXED, __HIP_MEMORY_SCOPE_AGENT);
      }
      unsigned long long v = 0;
      for (;;) {
        if (tid < NBLK)
          v = __hip_atomic_load(&sb[tid], __ATOMIC_RELAXED, __HIP_MEMORY_SCOPE_AGENT);
        const bool ok = (tid < NBLK) ? ((v >> 45) == (unsigned long long)s) : true;
        if (__all(ok)) break;
        __builtin_amdgcn_s_sleep(1);
      }
#pragma unroll
      for (int off = 8; off; off >>= 1) {
        unsigned long long o = __shfl_xor(v, off);
        v = v > o ? v : o;
      }
      if (tid == 0) far_sh = 8191 - (int)(v & 0x1FFFu);
    }
    __syncthreads();
    far = far_sh;
    if (blk == 0 && tid == 0) out[b * NPT + s] = far;
  }
}

// ======================= host =======================

extern "C" void kernel_launch(void* const* d_in, const int* in_sizes, int n_in,
                              void* d_out, int out_size, void* d_ws, size_t ws_size,
                              hipStream_t stream) {
  const float* pts  = (const float*)d_in[0];
  const float* feat = (const float*)d_in[1];
  int* out = (int*)d_out;

  const size_t oneD = (size_t)NN * NN * sizeof(float);   // 256 MiB
  if (ws_size >= 2 * oneD) {
    float* D = (float*)d_ws;
    for (int b = 0; b < BB; ++b)
      dist_kernel<<<NT * NT, 256, 0, stream>>>(
          pts + (size_t)b * NN * 3, feat + (size_t)b * CC * NN, D + (size_t)b * NN * NN);
    scan_kernel<<<BB, 512, 0, stream>>>(D, (unsigned long long)NN * NN, out, NPT);
  } else if (ws_size >= oneD) {
    float* D = (float*)d_ws;
    for (int b = 0; b < BB; ++b) {
      dist_kernel<<<NT * NT, 256, 0, stream>>>(
          pts + (size_t)b * NN * 3, feat + (size_t)b * CC * NN, D);
      scan_kernel<<<1, 512, 0, stream>>>(D, 0, out + (size_t)b * NPT, 0);
    }
  } else {
    unsigned long long* slots = (unsigned long long*)d_ws; // [2][BB][NBLK] = 512 B
    hipMemsetAsync(d_ws, 0, 2 * BB * NBLK * sizeof(unsigned long long), stream);
    void* args[] = {(void*)&pts, (void*)&feat, (void*)&out, (void*)&slots};
    dim3 grid(BB * NBLK), block(TPB);
    hipLaunchCooperativeKernel((void*)fps_fallback, grid, block, args, 0, stream);
  }
}